// Round 1
// baseline (266.372 us; speedup 1.0000x reference)
//
#include <hip/hip_runtime.h>
#include <cstdint>
#include <cstddef>

#define BS 8
#define NQ 16384
#define NG 1024
#define NC 5
#define GT 8
#define THREADS 256

using u64 = unsigned long long;

// compare-exchange ascending
__device__ __forceinline__ void ce(u64 &x, u64 &y) {
    u64 lo = x < y ? x : y;
    u64 hi = x < y ? y : x;
    x = lo; y = hi;
}

// merge sorted-ascending a[0..3] with sorted-ascending {b0..b3}, keep 4 smallest in a (sorted)
__device__ __forceinline__ void merge4(u64 a[4], u64 b0, u64 b1, u64 b2, u64 b3) {
    // bitonic half-cleaner: element-wise min of a with reversed b -> contains 4 smallest, bitonic
    u64 m0 = a[0] < b3 ? a[0] : b3;
    u64 m1 = a[1] < b2 ? a[1] : b2;
    u64 m2 = a[2] < b1 ? a[2] : b1;
    u64 m3 = a[3] < b0 ? a[3] : b0;
    // sort bitonic sequence of 4
    ce(m0, m2); ce(m1, m3); ce(m0, m1); ce(m2, m3);
    a[0] = m0; a[1] = m1; a[2] = m2; a[3] = m3;
}

// probs[b][c][q] = softmax(logits[b][q][:])[c]  (class-major for coalesced reads)
__global__ void softmax_kernel(const float* __restrict__ logits, float* __restrict__ probs) {
    int idx = blockIdx.x * blockDim.x + threadIdx.x;  // = b*NQ + q
    if (idx >= BS * NQ) return;
    int b = idx / NQ, q = idx - b * NQ;
    float x[NC];
    float mx = -3.0e38f;
    #pragma unroll
    for (int c = 0; c < NC; ++c) { x[c] = logits[(size_t)idx * NC + c]; mx = fmaxf(mx, x[c]); }
    float s = 0.f;
    #pragma unroll
    for (int c = 0; c < NC; ++c) { x[c] = expf(x[c] - mx); s += x[c]; }
    #pragma unroll
    for (int c = 0; c < NC; ++c) probs[((size_t)b * NC + c) * NQ + q] = x[c] / s;
}

__global__ __launch_bounds__(THREADS) void match_kernel(
        const float* __restrict__ pred_coords,   // [BS][NQ][2]
        const float* __restrict__ probs,         // [BS][NC][NQ]
        const float* __restrict__ gt_coords,     // [BS][NG][2]
        const int*   __restrict__ gt_labels,     // [BS][NG]
        const int*   __restrict__ gt_masks,      // [BS][NG]
        int*         __restrict__ out)           // [BS][4][NG]
{
    int blk = blockIdx.x;
    int b  = blk / (NG / GT);
    int g0 = (blk % (NG / GT)) * GT;
    int tid = threadIdx.x;

    float gx[GT], gy[GT], gb2[GT];
    const float* pprob[GT];
    #pragma unroll
    for (int i = 0; i < GT; ++i) {
        int g = g0 + i;
        float2 gc = reinterpret_cast<const float2*>(gt_coords)[(size_t)b * NG + g];
        gx[i] = gc.x; gy[i] = gc.y;
        gb2[i] = gc.x * gc.x + gc.y * gc.y;
        int lab = gt_labels[b * NG + g];
        pprob[i] = probs + ((size_t)b * NC + lab) * NQ;
    }

    u64 key[GT][4];
    #pragma unroll
    for (int i = 0; i < GT; ++i) {
        #pragma unroll
        for (int j = 0; j < 4; ++j) key[i][j] = ~0ull;
    }

    const float2* pc = reinterpret_cast<const float2*>(pred_coords) + (size_t)b * NQ;
    for (int q = tid; q < NQ; q += THREADS) {
        float2 c = pc[q];
        float a2 = c.x * c.x + c.y * c.y;
        #pragma unroll
        for (int i = 0; i < GT; ++i) {
            float p  = pprob[i][q];
            float ab = c.x * gx[i] + c.y * gy[i];
            float d2 = fmaxf(a2 + gb2[i] - 2.0f * ab, 0.0f);
            float cost = 0.1f * sqrtf(d2) - p;
            // orderable-uint transform (ascending float order, handles negatives)
            unsigned u = __float_as_uint(cost);
            u ^= ((unsigned)((int)u >> 31)) | 0x80000000u;
            u64 k = ((u64)u << 32) | (unsigned)q;   // tie-break: lower q wins
            if (k < key[i][3]) {
                key[i][3] = k;
                ce(key[i][2], key[i][3]);
                ce(key[i][1], key[i][2]);
                ce(key[i][0], key[i][1]);
            }
        }
    }

    // 64-lane butterfly merge (all lanes converge to wave top-4)
    #pragma unroll
    for (int d = 1; d < 64; d <<= 1) {
        #pragma unroll
        for (int i = 0; i < GT; ++i) {
            u64 b0 = __shfl_xor(key[i][0], d, 64);
            u64 b1 = __shfl_xor(key[i][1], d, 64);
            u64 b2 = __shfl_xor(key[i][2], d, 64);
            u64 b3 = __shfl_xor(key[i][3], d, 64);
            merge4(key[i], b0, b1, b2, b3);
        }
    }

    __shared__ u64 lds[THREADS / 64][GT][4];
    int wave = tid >> 6, lane = tid & 63;
    if (lane == 0) {
        #pragma unroll
        for (int i = 0; i < GT; ++i) {
            #pragma unroll
            for (int j = 0; j < 4; ++j) lds[wave][i][j] = key[i][j];
        }
    }
    __syncthreads();

    if (tid < GT) {
        u64 fin[4];
        #pragma unroll
        for (int j = 0; j < 4; ++j) fin[j] = lds[0][tid][j];
        #pragma unroll
        for (int w = 1; w < THREADS / 64; ++w)
            merge4(fin, lds[w][tid][0], lds[w][tid][1], lds[w][tid][2], lds[w][tid][3]);
        int g = g0 + tid;
        int m = gt_masks[b * NG + g];
        #pragma unroll
        for (int j = 0; j < 4; ++j) {
            // masked-out gt: C = +inf everywhere -> top_k of equal values = indices 0..3
            int idx = m ? (int)(fin[j] & 0xFFFFFFFFull) : j;
            out[((size_t)b * 4 + j) * NG + g] = idx;
        }
    }
}

extern "C" void kernel_launch(void* const* d_in, const int* in_sizes, int n_in,
                              void* d_out, int out_size, void* d_ws, size_t ws_size,
                              hipStream_t stream) {
    const float* pred_coords = (const float*)d_in[0];
    const float* pred_logits = (const float*)d_in[1];
    const float* gt_coords   = (const float*)d_in[2];
    const int*   gt_labels   = (const int*)d_in[3];
    const int*   gt_masks    = (const int*)d_in[4];
    int* out = (int*)d_out;
    float* probs = (float*)d_ws;   // needs BS*NC*NQ*4 = 2.62 MB

    softmax_kernel<<<(BS * NQ) / THREADS, THREADS, 0, stream>>>(pred_logits, probs);
    match_kernel<<<BS * (NG / GT), THREADS, 0, stream>>>(
        pred_coords, probs, gt_coords, gt_labels, gt_masks, out);
}

// Round 2
// 50.701 us; speedup vs baseline: 5.2538x; 5.2538x over previous
//
#include <hip/hip_runtime.h>
#include <cstdint>
#include <cstddef>

#define BS 8
#define NQ 16384
#define NG 1024
#define NC 5
#define GT 8
#define THREADS 256
#define NBC (BS * NC)        // 40
#define CHUNKS1A 16          // part_kernel chunks per (b,c), 1024 q each
#define SLACK 0.1514214f     // 0.1*sqrt(2) + 0.01 rounding margin
#define FINF 3.0e38f

using u64 = unsigned long long;

// ---------- float top-4 helpers (keep 4 smallest, sorted ascending) ----------
__device__ __forceinline__ void fce(float &x, float &y) {
    float lo = fminf(x, y), hi = fmaxf(x, y);
    x = lo; y = hi;
}
__device__ __forceinline__ void finsert(float k[4], float v) {
    float c = v, t;
    t = fminf(k[0], c); c = fmaxf(k[0], c); k[0] = t;
    t = fminf(k[1], c); c = fmaxf(k[1], c); k[1] = t;
    t = fminf(k[2], c); c = fmaxf(k[2], c); k[2] = t;
    k[3] = fminf(k[3], c);
}
__device__ __forceinline__ void fmerge4(float a[4], float b0, float b1, float b2, float b3) {
    float m0 = fminf(a[0], b3), m1 = fminf(a[1], b2), m2 = fminf(a[2], b1), m3 = fminf(a[3], b0);
    fce(m0, m2); fce(m1, m3); fce(m0, m1); fce(m2, m3);
    a[0] = m0; a[1] = m1; a[2] = m2; a[3] = m3;
}

// ---------- u64 keyed top-4 helpers (exact, tie-break by low 32 = q) ----------
__device__ __forceinline__ void ce(u64 &x, u64 &y) {
    u64 lo = x < y ? x : y;
    u64 hi = x < y ? y : x;
    x = lo; y = hi;
}
__device__ __forceinline__ void merge4(u64 a[4], u64 b0, u64 b1, u64 b2, u64 b3) {
    u64 m0 = a[0] < b3 ? a[0] : b3;
    u64 m1 = a[1] < b2 ? a[1] : b2;
    u64 m2 = a[2] < b1 ? a[2] : b1;
    u64 m3 = a[3] < b0 ? a[3] : b0;
    ce(m0, m2); ce(m1, m3); ce(m0, m1); ce(m2, m3);
    a[0] = m0; a[1] = m1; a[2] = m2; a[3] = m3;
}

// softmax numerics — must be the same expression everywhere
#define SOFTMAX5(lg, X0, X1, X2, X3, X4, S)                                   \
    float X0 = (lg)[0], X1 = (lg)[1], X2 = (lg)[2], X3 = (lg)[3], X4 = (lg)[4]; \
    {                                                                          \
        float mx_ = fmaxf(fmaxf(fmaxf(X0, X1), fmaxf(X2, X3)), X4);            \
        X0 = expf(X0 - mx_); X1 = expf(X1 - mx_); X2 = expf(X2 - mx_);         \
        X3 = expf(X3 - mx_); X4 = expf(X4 - mx_);                              \
    }                                                                          \
    float S = X0 + X1 + X2 + X3 + X4;

// ---------- kernel 1a: per-(b,c,chunk) top-4 of p_c (negated, ascending) ----------
__global__ __launch_bounds__(THREADS) void part_kernel(const float* __restrict__ logits,
                                                       float* __restrict__ p4part) {
    int blk = blockIdx.x;                 // 640
    int bc = blk / CHUNKS1A, chunk = blk % CHUNKS1A;
    int b = bc / NC, c = bc % NC;
    int tid = threadIdx.x;
    const float* lgb = logits + (size_t)b * NQ * NC;

    float nk[4] = {FINF, FINF, FINF, FINF};
    #pragma unroll
    for (int r = 0; r < 4; ++r) {
        int q = chunk * 1024 + r * 256 + tid;
        const float* lg = lgb + (size_t)q * NC;
        SOFTMAX5(lg, x0, x1, x2, x3, x4, s);
        float num = (c == 0) ? x0 : (c == 1) ? x1 : (c == 2) ? x2 : (c == 3) ? x3 : x4;
        float p = num / s;
        finsert(nk, -p);
    }
    #pragma unroll
    for (int d = 1; d < 64; d <<= 1) {
        float b0 = __shfl_xor(nk[0], d, 64);
        float b1 = __shfl_xor(nk[1], d, 64);
        float b2 = __shfl_xor(nk[2], d, 64);
        float b3 = __shfl_xor(nk[3], d, 64);
        fmerge4(nk, b0, b1, b2, b3);
    }
    __shared__ float lds[4][4];
    int wave = tid >> 6, lane = tid & 63;
    if (lane == 0) {
        #pragma unroll
        for (int j = 0; j < 4; ++j) lds[wave][j] = nk[j];
    }
    __syncthreads();
    if (tid == 0) {
        #pragma unroll
        for (int w = 1; w < 4; ++w) fmerge4(nk, lds[w][0], lds[w][1], lds[w][2], lds[w][3]);
        #pragma unroll
        for (int j = 0; j < 4; ++j) p4part[(bc * CHUNKS1A + chunk) * 4 + j] = nk[j];
    }
}

// ---------- kernel 1b: reduce 64 partials -> threshold; zero counters ----------
__global__ void thresh_kernel(const float* __restrict__ p4part,
                              float* __restrict__ T, unsigned* __restrict__ count) {
    int bc = blockIdx.x;                  // 40 blocks, 64 threads
    int lane = threadIdx.x;
    float v = p4part[bc * 64 + lane];
    float a[4] = {v, FINF, FINF, FINF};
    #pragma unroll
    for (int d = 1; d < 64; d <<= 1) {
        float b0 = __shfl_xor(a[0], d, 64);
        float b1 = __shfl_xor(a[1], d, 64);
        float b2 = __shfl_xor(a[2], d, 64);
        float b3 = __shfl_xor(a[3], d, 64);
        fmerge4(a, b0, b1, b2, b3);
    }
    if (lane == 0) {
        T[bc] = -a[3] - SLACK;    // P4* - slack
        count[bc] = 0u;
    }
}

// ---------- kernel 1c: compact candidates (q, p) per (b,c) ----------
__global__ __launch_bounds__(THREADS) void compact_kernel(const float* __restrict__ logits,
                                                          const float* __restrict__ T,
                                                          unsigned* __restrict__ count,
                                                          u64* __restrict__ clist, int CAP) {
    int blk = blockIdx.x;                 // 256 = 8 b * 32 chunks of 512 q
    int b = blk / 32, chunk = blk % 32;
    int tid = threadIdx.x;
    const float* lgb = logits + (size_t)b * NQ * NC;
    float T0 = T[b * NC + 0], T1 = T[b * NC + 1], T2 = T[b * NC + 2],
          T3 = T[b * NC + 3], T4 = T[b * NC + 4];

    #pragma unroll
    for (int r = 0; r < 2; ++r) {
        int q = chunk * 512 + r * 256 + tid;
        const float* lg = lgb + (size_t)q * NC;
        SOFTMAX5(lg, x0, x1, x2, x3, x4, s);
        float p0 = x0 / s, p1 = x1 / s, p2 = x2 / s, p3 = x3 / s, p4 = x4 / s;
        #define APPEND(P, C)                                                            \
            if ((P) >= T##C) {                                                          \
                unsigned slot = atomicAdd(&count[b * NC + C], 1u);                      \
                if (slot < (unsigned)CAP)                                               \
                    clist[(size_t)(b * NC + C) * CAP + slot] =                          \
                        ((u64)__float_as_uint(P) << 32) | (unsigned)q;                  \
            }
        APPEND(p0, 0) APPEND(p1, 1) APPEND(p2, 2) APPEND(p3, 3) APPEND(p4, 4)
        #undef APPEND
    }
}

// ---------- kernel 2: exact keyed top-4 over candidates (brute fallback on overflow) ----------
__global__ __launch_bounds__(THREADS) void match_kernel(
        const float* __restrict__ pred_coords,   // [BS][NQ][2]
        const float* __restrict__ logits,        // [BS][NQ][NC]
        const float* __restrict__ gt_coords,     // [BS][NG][2]
        const int*   __restrict__ gt_labels,     // [BS][NG]
        const int*   __restrict__ gt_masks,      // [BS][NG]
        const unsigned* __restrict__ count,
        const u64*   __restrict__ clist, int CAP,
        int*         __restrict__ out)           // [BS][4][NG]
{
    int blk = blockIdx.x;
    int b  = blk / (NG / GT);
    int g0 = (blk % (NG / GT)) * GT;
    int tid = threadIdx.x;
    int wave = tid >> 6, lane = tid & 63;
    const float2* pc  = reinterpret_cast<const float2*>(pred_coords) + (size_t)b * NQ;
    const float*  lgb = logits + (size_t)b * NQ * NC;

    __shared__ u64 lds[THREADS / 64][GT][4];

    for (int i = 0; i < GT; ++i) {
        int g = g0 + i;
        u64 kk[4] = {~0ull, ~0ull, ~0ull, ~0ull};
        if (gt_masks[b * NG + g]) {
            int c = gt_labels[b * NG + g];
            float2 gc = reinterpret_cast<const float2*>(gt_coords)[(size_t)b * NG + g];
            float gx = gc.x, gy = gc.y, gb2 = gc.x * gc.x + gc.y * gc.y;
            unsigned n = count[b * NC + c];
            if (n <= (unsigned)CAP) {
                const u64* lst = clist + (size_t)(b * NC + c) * CAP;
                for (unsigned j = tid; j < n; j += THREADS) {
                    u64 e = lst[j];
                    float p = __uint_as_float((unsigned)(e >> 32));
                    unsigned q = (unsigned)(e & 0xFFFFFFFFu);
                    float2 cq = pc[q];
                    float a2 = cq.x * cq.x + cq.y * cq.y;
                    float ab = cq.x * gx + cq.y * gy;
                    float d2 = fmaxf(a2 + gb2 - 2.0f * ab, 0.0f);
                    float cost = 0.1f * sqrtf(d2) - p;
                    unsigned u = __float_as_uint(cost);
                    u ^= ((unsigned)((int)u >> 31)) | 0x80000000u;
                    u64 k = ((u64)u << 32) | q;
                    if (k < kk[3]) { kk[3] = k; ce(kk[2], kk[3]); ce(kk[1], kk[2]); ce(kk[0], kk[1]); }
                }
            } else {
                // capacity overflow: exact brute-force for this gt (always correct)
                for (int q = tid; q < NQ; q += THREADS) {
                    const float* lg = lgb + (size_t)q * NC;
                    SOFTMAX5(lg, x0, x1, x2, x3, x4, s);
                    float num = (c == 0) ? x0 : (c == 1) ? x1 : (c == 2) ? x2 : (c == 3) ? x3 : x4;
                    float p = num / s;
                    float2 cq = pc[q];
                    float a2 = cq.x * cq.x + cq.y * cq.y;
                    float ab = cq.x * gx + cq.y * gy;
                    float d2 = fmaxf(a2 + gb2 - 2.0f * ab, 0.0f);
                    float cost = 0.1f * sqrtf(d2) - p;
                    unsigned u = __float_as_uint(cost);
                    u ^= ((unsigned)((int)u >> 31)) | 0x80000000u;
                    u64 k = ((u64)u << 32) | (unsigned)q;
                    if (k < kk[3]) { kk[3] = k; ce(kk[2], kk[3]); ce(kk[1], kk[2]); ce(kk[0], kk[1]); }
                }
            }
            #pragma unroll
            for (int d = 1; d < 64; d <<= 1) {
                u64 b0 = __shfl_xor(kk[0], d, 64);
                u64 b1 = __shfl_xor(kk[1], d, 64);
                u64 b2 = __shfl_xor(kk[2], d, 64);
                u64 b3 = __shfl_xor(kk[3], d, 64);
                merge4(kk, b0, b1, b2, b3);
            }
        }
        if (lane == 0) {
            #pragma unroll
            for (int j = 0; j < 4; ++j) lds[wave][i][j] = kk[j];
        }
    }
    __syncthreads();

    if (tid < GT) {
        u64 fin[4];
        #pragma unroll
        for (int j = 0; j < 4; ++j) fin[j] = lds[0][tid][j];
        #pragma unroll
        for (int w = 1; w < THREADS / 64; ++w)
            merge4(fin, lds[w][tid][0], lds[w][tid][1], lds[w][tid][2], lds[w][tid][3]);
        int g = g0 + tid;
        int m = gt_masks[b * NG + g];
        #pragma unroll
        for (int j = 0; j < 4; ++j) {
            int idx = m ? (int)(fin[j] & 0xFFFFFFFFull) : j;
            out[((size_t)b * 4 + j) * NG + g] = idx;
        }
    }
}

extern "C" void kernel_launch(void* const* d_in, const int* in_sizes, int n_in,
                              void* d_out, int out_size, void* d_ws, size_t ws_size,
                              hipStream_t stream) {
    const float* pred_coords = (const float*)d_in[0];
    const float* pred_logits = (const float*)d_in[1];
    const float* gt_coords   = (const float*)d_in[2];
    const int*   gt_labels   = (const int*)d_in[3];
    const int*   gt_masks    = (const int*)d_in[4];
    int* out = (int*)d_out;

    char* ws = (char*)d_ws;
    float*    p4part = (float*)ws;              // 8*5*16*4 floats = 10240 B
    float*    T      = (float*)(ws + 10240);    // 40 floats
    unsigned* count  = (unsigned*)(ws + 10432); // 40 u32
    u64*      clist  = (u64*)(ws + 16384);

    int CAP = 16384;
    long long avail = (long long)ws_size - 16384;
    long long per = (long long)NBC * 8;
    if (avail < (long long)CAP * per) CAP = (int)(avail / per);
    if (CAP < 1) CAP = 1;                       // fallback path covers tiny ws

    part_kernel  <<<NBC * CHUNKS1A, THREADS, 0, stream>>>(pred_logits, p4part);
    thresh_kernel<<<NBC, 64, 0, stream>>>(p4part, T, count);
    compact_kernel<<<BS * 32, THREADS, 0, stream>>>(pred_logits, T, count, clist, CAP);
    match_kernel <<<BS * (NG / GT), THREADS, 0, stream>>>(
        pred_coords, pred_logits, gt_coords, gt_labels, gt_masks, count, clist, CAP, out);
}